// Round 2
// baseline (634.557 us; speedup 1.0000x reference)
//
#include <hip/hip_runtime.h>

#define LSZ 8192

// ---------------------------------------------------------------------------
// transp_k: x[B=32][L][C=32] -> xt[L][C=32][B=32]
// block = 256 threads handles 8 positions. LDS stride 1057 (odd vs 32 banks)
// keeps both phases ~2-way conflicted (free).
// ---------------------------------------------------------------------------
__global__ __launch_bounds__(256)
void transp_k(const float* __restrict__ x, float* __restrict__ xt)
{
    __shared__ float lds[8454];
    const int t    = threadIdx.x;
    const int l0   = blockIdx.x * 8;
    const int lane = t & 63;

    #pragma unroll
    for (int it = 0; it < 8; ++it) {
        int b  = it * 4 + (t >> 6);
        int l  = lane >> 3;
        int c4 = (lane & 7) * 4;
        float4 v = *reinterpret_cast<const float4*>(x + ((size_t)b * LSZ + l0 + l) * 32 + c4);
        float* p = lds + l * 1057 + c4 * 33 + b;
        p[0] = v.x; p[33] = v.y; p[66] = v.z; p[99] = v.w;
    }
    __syncthreads();
    #pragma unroll
    for (int it = 0; it < 8; ++it) {
        int l  = it;
        int c  = t >> 3;
        int b0 = (t & 7) * 4;
        const float* p = lds + l * 1057 + c * 33 + b0;
        float4 v = {p[0], p[1], p[2], p[3]};
        *reinterpret_cast<float4*>(xt + ((size_t)(l0 + l) << 10) + c * 32 + b0) = v;
    }
}

// ---------------------------------------------------------------------------
// lc_fast: one wave per position l, no LDS.
//   xin_t : [L][32][32]  (c-major, b contiguous)  — layer input (xt or ht)
//   wgt   : [5][L][32][32] ([tap][l][c][f])
//   out   : mode 0 -> ht[L][32][32] ([l][f][b], transposed store)
//           mode 1 -> out[B][L][32] + residual from xres[B][L][32]
// Lane map: fi = lane&7 (4 f each), bg = lane>>3 (4 b each); 4x4 register tile.
// W double-buffered in 8-c chunks (8 dwordx4 in flight), x just-in-time (L2).
// ---------------------------------------------------------------------------
__global__ __launch_bounds__(256, 4)
void lc_fast(const float* __restrict__ xin_t,
             const float* __restrict__ wgt,
             const float* __restrict__ bias,
             const float* __restrict__ gamma,
             const float* __restrict__ beta,
             const float* __restrict__ mean,
             const float* __restrict__ var,
             const float* __restrict__ xres,
             float* __restrict__ out,
             int mode)
{
    const int tid  = threadIdx.x;
    const int bid  = blockIdx.x;
    const int bs   = ((bid & 7) << 8) | (bid >> 3);   // XCD-chunked swizzle (2048 blocks)
    const int wl   = tid >> 6;
    const int lane = tid & 63;
    const int l    = (bs << 2) | wl;
    const int fi   = lane & 7;
    const int bg   = lane >> 3;

    const float* xr0 = xin_t + ((size_t)l << 10) + (bg << 2);
    const float* xr2 = xin_t + ((size_t)((l - 1) & (LSZ - 1)) << 10) + (bg << 2);
    const float* xr3 = xin_t + ((size_t)((l + 1) & (LSZ - 1)) << 10) + (bg << 2);
    const float* xr4 = xin_t + ((size_t)((l - 2) & (LSZ - 1)) << 10) + (bg << 2);

    float4 acc[4];
    acc[0] = acc[1] = acc[2] = acc[3] = float4{0.f, 0.f, 0.f, 0.f};

    const float* wbase = wgt + ((size_t)l << 10) + (fi << 2);

    float4 wb[8], xb[8];
    #pragma unroll
    for (int u = 0; u < 8; ++u)
        wb[u] = *reinterpret_cast<const float4*>(wbase + u * 32);

    #pragma unroll
    for (int k = 0; k < 20; ++k) {
        const int i  = k >> 2;
        const int c0 = (k & 3) * 8;
        const float* xrow_ = (i <= 1) ? xr0 : (i == 2 ? xr2 : (i == 3 ? xr3 : xr4));

        #pragma unroll
        for (int u = 0; u < 8; ++u)
            xb[u] = *reinterpret_cast<const float4*>(xrow_ + (c0 + u) * 32);

        float4 wn[8];
        if (k < 19) {
            const int kn = k + 1;
            const float* wp_ = wbase + (size_t)(kn >> 2) * (LSZ * 1024) + ((kn & 3) * 8) * 32;
            #pragma unroll
            for (int u = 0; u < 8; ++u)
                wn[u] = *reinterpret_cast<const float4*>(wp_ + u * 32);
        }

        #pragma unroll
        for (int u = 0; u < 8; ++u) {
            const float4 w4 = wb[u];
            const float4 x4 = xb[u];
            acc[0].x = fmaf(x4.x, w4.x, acc[0].x); acc[0].y = fmaf(x4.x, w4.y, acc[0].y);
            acc[0].z = fmaf(x4.x, w4.z, acc[0].z); acc[0].w = fmaf(x4.x, w4.w, acc[0].w);
            acc[1].x = fmaf(x4.y, w4.x, acc[1].x); acc[1].y = fmaf(x4.y, w4.y, acc[1].y);
            acc[1].z = fmaf(x4.y, w4.z, acc[1].z); acc[1].w = fmaf(x4.y, w4.w, acc[1].w);
            acc[2].x = fmaf(x4.z, w4.x, acc[2].x); acc[2].y = fmaf(x4.z, w4.y, acc[2].y);
            acc[2].z = fmaf(x4.z, w4.z, acc[2].z); acc[2].w = fmaf(x4.z, w4.w, acc[2].w);
            acc[3].x = fmaf(x4.w, w4.x, acc[3].x); acc[3].y = fmaf(x4.w, w4.y, acc[3].y);
            acc[3].z = fmaf(x4.w, w4.z, acc[3].z); acc[3].w = fmaf(x4.w, w4.w, acc[3].w);
        }

        if (k < 19) {
            #pragma unroll
            for (int u = 0; u < 8; ++u) wb[u] = wn[u];
        }
    }

    // ---- epilogue ----
    const int f0 = fi << 2;
    float4 g4 = *reinterpret_cast<const float4*>(gamma + f0);
    float4 t4 = *reinterpret_cast<const float4*>(beta  + f0);
    float4 m4 = *reinterpret_cast<const float4*>(mean  + f0);
    float4 v4 = *reinterpret_cast<const float4*>(var   + f0);
    float4 sc, sh;
    sc.x = g4.x * rsqrtf(v4.x + 1e-3f); sh.x = t4.x - m4.x * sc.x;
    sc.y = g4.y * rsqrtf(v4.y + 1e-3f); sh.y = t4.y - m4.y * sc.y;
    sc.z = g4.z * rsqrtf(v4.z + 1e-3f); sh.z = t4.z - m4.z * sc.z;
    sc.w = g4.w * rsqrtf(v4.w + 1e-3f); sh.w = t4.w - m4.w * sc.w;
    float4 bb = *reinterpret_cast<const float4*>(bias + l * 32 + f0);

    if (mode == 0) {
        // transposed store into ht[l][f][b]
        float4 tb[4];
        tb[0] = float4{acc[0].x, acc[1].x, acc[2].x, acc[3].x};
        tb[1] = float4{acc[0].y, acc[1].y, acc[2].y, acc[3].y};
        tb[2] = float4{acc[0].z, acc[1].z, acc[2].z, acc[3].z};
        tb[3] = float4{acc[0].w, acc[1].w, acc[2].w, acc[3].w};
        const float scv[4] = {sc.x, sc.y, sc.z, sc.w};
        const float shv[4] = {sh.x, sh.y, sh.z, sh.w};
        const float bbv[4] = {bb.x, bb.y, bb.z, bb.w};
        #pragma unroll
        for (int jf = 0; jf < 4; ++jf) {
            float s_ = scv[jf], h_ = shv[jf], b_ = bbv[jf];
            float4 t = tb[jf];
            t.x = (t.x + 2.f * b_) * s_ + h_;
            t.y = (t.y + 2.f * b_) * s_ + h_;
            t.z = (t.z + 2.f * b_) * s_ + h_;
            t.w = (t.w + 2.f * b_) * s_ + h_;
            t.x = t.x >= 0.f ? t.x : 0.3f * t.x;
            t.y = t.y >= 0.f ? t.y : 0.3f * t.y;
            t.z = t.z >= 0.f ? t.z : 0.3f * t.z;
            t.w = t.w >= 0.f ? t.w : 0.3f * t.w;
            *reinterpret_cast<float4*>(out + ((size_t)l << 10) + (f0 + jf) * 32 + (bg << 2)) = t;
        }
    } else {
        #pragma unroll
        for (int j = 0; j < 4; ++j) {
            int b = (bg << 2) + j;
            size_t off = ((size_t)b * LSZ + l) * 32 + f0;
            float4 t = acc[j];
            t.x = (t.x + 2.f * bb.x) * sc.x + sh.x;
            t.y = (t.y + 2.f * bb.y) * sc.y + sh.y;
            t.z = (t.z + 2.f * bb.z) * sc.z + sh.z;
            t.w = (t.w + 2.f * bb.w) * sc.w + sh.w;
            float4 r = *reinterpret_cast<const float4*>(xres + off);
            t.x += r.x; t.y += r.y; t.z += r.z; t.w += r.w;
            t.x = t.x >= 0.f ? t.x : 0.3f * t.x;
            t.y = t.y >= 0.f ? t.y : 0.3f * t.y;
            t.z = t.z >= 0.f ? t.z : 0.3f * t.z;
            t.w = t.w >= 0.f ? t.w : 0.3f * t.w;
            *reinterpret_cast<float4*>(out + off) = t;
        }
    }
}

extern "C" void kernel_launch(void* const* d_in, const int* in_sizes, int n_in,
                              void* d_out, int out_size, void* d_ws, size_t ws_size,
                              hipStream_t stream) {
    const float* x   = (const float*)d_in[0];
    const float* k1  = (const float*)d_in[1];
    const float* b1  = (const float*)d_in[2];
    const float* g1  = (const float*)d_in[3];
    const float* be1 = (const float*)d_in[4];
    const float* mn1 = (const float*)d_in[5];
    const float* vr1 = (const float*)d_in[6];
    const float* k2  = (const float*)d_in[7];
    const float* b2  = (const float*)d_in[8];
    const float* g2  = (const float*)d_in[9];
    const float* be2 = (const float*)d_in[10];
    const float* mn2 = (const float*)d_in[11];
    const float* vr2 = (const float*)d_in[12];

    float* xt = (float*)d_ws;                          // [L][32][32]
    float* ht = xt + (size_t)LSZ * 1024;               // [L][32][32]
    float* o  = (float*)d_out;

    hipLaunchKernelGGL(transp_k, dim3(1024), dim3(256), 0, stream, x, xt);
    hipLaunchKernelGGL(lc_fast, dim3(2048), dim3(256), 0, stream,
                       xt, k1, b1, g1, be1, mn1, vr1, (const float*)nullptr, ht, 0);
    hipLaunchKernelGGL(lc_fast, dim3(2048), dim3(256), 0, stream,
                       ht, k2, b2, g2, be2, mn2, vr2, x, o, 1);
}

// Round 7
// 391.140 us; speedup vs baseline: 1.6223x; 1.6223x over previous
//
#include <hip/hip_runtime.h>

#define LSZ 8192
#define STR 40                 // padded LDS row stride in f16 (80 B = 5*16 -> b128-aligned)
#define XROWS 11               // 8 positions + halo [-2, +2]

typedef _Float16 f16;
typedef __attribute__((ext_vector_type(4))) _Float16 f16x4;
typedef __attribute__((ext_vector_type(8))) _Float16 f16x8;
typedef __attribute__((ext_vector_type(4))) float f32x4;

// One wave per position l. A = x[b][c] (rows=b), B = w^T[c][f] staged as [f][c] f16,
// D[b][f] f32. 4 MFMA tiles (2 b-tiles x 2 f-tiles) x 5 taps, K=32 covers all c.
// Weights: per-wave private LDS double buffer, 2-deep tap prefetch via full-wave
// dwordx4 loads (1 KB/inst). No barriers after the x-stage sync.
__global__ __launch_bounds__(512, 4)
void lc_mfma(const void* __restrict__ xin_,
             const float* __restrict__ wgt,      // [5][L][32 c][32 f] f32
             const float* __restrict__ bias,     // [L][32]
             const float* __restrict__ gamma, const float* __restrict__ beta,
             const float* __restrict__ mean,  const float* __restrict__ var,
             const float* __restrict__ xres,     // [B][L][32] f32 (mode 1)
             void* __restrict__ out_, int mode)  // mode0: ht f16 [l][b][c]; mode1: f32 [b][l][c]
{
    __shared__ __align__(16) f16 xs[XROWS * 32 * STR];     // [row][b][c] f16
    __shared__ __align__(16) f16 ws[8 * 2 * 32 * STR];     // per-wave dbuf [f][c] f16

    const int tid  = threadIdx.x;
    const int wl   = tid >> 6;
    const int lane = tid & 63;
    const int bid  = blockIdx.x;
    const int bs   = ((bid & 7) << 7) | (bid >> 3);        // XCD-chunked swizzle (1024 = 8*128)
    const int l0   = bs << 3;
    const int l    = l0 + wl;
    const int fr   = lane & 15;                            // frag row/col within 16
    const int kg   = lane >> 4;                            // k-group (8 elems each)

    f16* wsw = ws + wl * (2 * 32 * STR);

    // ---- prologue: issue weight loads for taps 0,1 (in flight during x-stage) ----
    const int cb = lane >> 3;                              // c-block of 4 (8 blocks)
    const int fb = lane & 7;                               // f-block of 4 (8 blocks)
    const float* wbase = wgt + (size_t)l * 1024 + (size_t)(cb * 4) * 32 + fb * 4;
    float4 W[2][4];
    #pragma unroll
    for (int r = 0; r < 4; ++r)
        W[0][r] = *(const float4*)(wbase + (size_t)0 * LSZ * 1024 + r * 32);
    #pragma unroll
    for (int r = 0; r < 4; ++r)
        W[1][r] = *(const float4*)(wbase + (size_t)1 * LSZ * 1024 + r * 32);

    // ---- stage x tile (rows l0-2 .. l0+8) into xs as f16 ----
    {
        const int b = lane >> 1, ch = lane & 1;            // 32 B per lane per row
        if (mode == 0) {
            const float* xf = (const float*)xin_;          // [b][l][c] f32
            for (int r = wl; r < XROWS; r += 8) {
                int p = (l0 - 2 + r) & (LSZ - 1);
                const float* src = xf + ((size_t)b * LSZ + p) * 32 + ch * 16;
                float4 v0 = *(const float4*)(src + 0);
                float4 v1 = *(const float4*)(src + 4);
                float4 v2 = *(const float4*)(src + 8);
                float4 v3 = *(const float4*)(src + 12);
                f16x8 h0, h1;
                h0[0]=(f16)v0.x; h0[1]=(f16)v0.y; h0[2]=(f16)v0.z; h0[3]=(f16)v0.w;
                h0[4]=(f16)v1.x; h0[5]=(f16)v1.y; h0[6]=(f16)v1.z; h0[7]=(f16)v1.w;
                h1[0]=(f16)v2.x; h1[1]=(f16)v2.y; h1[2]=(f16)v2.z; h1[3]=(f16)v2.w;
                h1[4]=(f16)v3.x; h1[5]=(f16)v3.y; h1[6]=(f16)v3.z; h1[7]=(f16)v3.w;
                *(f16x8*)&xs[(r * 32 + b) * STR + ch * 16 + 0] = h0;
                *(f16x8*)&xs[(r * 32 + b) * STR + ch * 16 + 8] = h1;
            }
        } else {
            const f16* xh = (const f16*)xin_;              // [l][b][c] f16
            for (int r = wl; r < XROWS; r += 8) {
                int p = (l0 - 2 + r) & (LSZ - 1);
                const f16* src = xh + (size_t)p * 1024 + b * 32 + ch * 16;
                f16x8 h0 = *(const f16x8*)(src + 0);
                f16x8 h1 = *(const f16x8*)(src + 8);
                *(f16x8*)&xs[(r * 32 + b) * STR + ch * 16 + 0] = h0;
                *(f16x8*)&xs[(r * 32 + b) * STR + ch * 16 + 8] = h1;
            }
        }
    }
    __syncthreads();

    // ---- per-lane BN constants and bias ----
    float scA = gamma[fr]      * rsqrtf(var[fr]      + 1e-3f);
    float shA = beta[fr]       - mean[fr]      * scA;
    float scB = gamma[16 + fr] * rsqrtf(var[16 + fr] + 1e-3f);
    float shB = beta[16 + fr]  - mean[16 + fr] * scB;
    float bA  = 2.f * bias[l * 32 + fr];
    float bB  = 2.f * bias[l * 32 + 16 + fr];

    f32x4 acc00 = {0.f,0.f,0.f,0.f}, acc01 = {0.f,0.f,0.f,0.f};
    f32x4 acc10 = {0.f,0.f,0.f,0.f}, acc11 = {0.f,0.f,0.f,0.f};

    // taps: step = {0,0,1,-1,2}; x-row offset = wl + 2 - step
    const int rof[5] = {2, 2, 1, 3, 0};

    #pragma unroll
    for (int i = 0; i < 5; ++i) {
        f16* buf = wsw + (i & 1) * (32 * STR);
        // transpose + cvt current weight set into [f][c] f16 (4 x ds_write_b64)
        #pragma unroll
        for (int q = 0; q < 4; ++q) {
            f16x4 h;
            h[0] = (f16)(((const float*)&W[i & 1][0])[q]);
            h[1] = (f16)(((const float*)&W[i & 1][1])[q]);
            h[2] = (f16)(((const float*)&W[i & 1][2])[q]);
            h[3] = (f16)(((const float*)&W[i & 1][3])[q]);
            *(f16x4*)&buf[(fb * 4 + q) * STR + cb * 4] = h;
        }
        // prefetch tap i+2 into the just-freed register set
        if (i < 3) {
            #pragma unroll
            for (int r = 0; r < 4; ++r)
                W[i & 1][r] = *(const float4*)(wbase + (size_t)(i + 2) * LSZ * 1024 + r * 32);
        }
        // fragments + 4 MFMA
        const int rr = wl + rof[i];
        f16x8 a0 = *(const f16x8*)&xs[(rr * 32 + fr     ) * STR + kg * 8];
        f16x8 a1 = *(const f16x8*)&xs[(rr * 32 + 16 + fr) * STR + kg * 8];
        f16x8 b0 = *(const f16x8*)&buf[(fr     ) * STR + kg * 8];
        f16x8 b1 = *(const f16x8*)&buf[(16 + fr) * STR + kg * 8];
        acc00 = __builtin_amdgcn_mfma_f32_16x16x32_f16(a0, b0, acc00, 0, 0, 0);
        acc01 = __builtin_amdgcn_mfma_f32_16x16x32_f16(a0, b1, acc01, 0, 0, 0);
        acc10 = __builtin_amdgcn_mfma_f32_16x16x32_f16(a1, b0, acc10, 0, 0, 0);
        acc11 = __builtin_amdgcn_mfma_f32_16x16x32_f16(a1, b1, acc11, 0, 0, 0);
    }

    // ---- epilogue ----
    if (mode == 0) {
        // BN + leaky, repack via this wave's LDS buffer -> ht[l][b][c] f16 (dwordx4 stores)
        f16* rp = wsw;   // 32*STR f16, private to this wave (taps done)
        #pragma unroll
        for (int bt = 0; bt < 2; ++bt) {
            f32x4 aA = bt ? acc10 : acc00;
            f32x4 aB = bt ? acc11 : acc01;
            #pragma unroll
            for (int j = 0; j < 4; ++j) {
                int b = bt * 16 + kg * 4 + j;
                float vA = (aA[j] + bA) * scA + shA;
                float vB = (aB[j] + bB) * scB + shB;
                vA = vA >= 0.f ? vA : 0.3f * vA;
                vB = vB >= 0.f ? vB : 0.3f * vB;
                rp[b * STR + fr]      = (f16)vA;
                rp[b * STR + 16 + fr] = (f16)vB;
            }
        }
        // wave-local write->read: DS ops are in-order within a wave; no barrier needed
        const int b2 = lane >> 1, ch = lane & 1;
        f16x8 r0 = *(const f16x8*)&rp[b2 * STR + ch * 16 + 0];
        f16x8 r1 = *(const f16x8*)&rp[b2 * STR + ch * 16 + 8];
        f16* oh = (f16*)out_;
        *(f16x8*)(oh + (size_t)l * 1024 + b2 * 32 + ch * 16 + 0) = r0;
        *(f16x8*)(oh + (size_t)l * 1024 + b2 * 32 + ch * 16 + 8) = r1;
    } else {
        // BN + residual + leaky -> out[b][l][f] f32
        float* of = (float*)out_;
        #pragma unroll
        for (int bt = 0; bt < 2; ++bt) {
            f32x4 aA = bt ? acc10 : acc00;
            f32x4 aB = bt ? acc11 : acc01;
            #pragma unroll
            for (int j = 0; j < 4; ++j) {
                int b = bt * 16 + kg * 4 + j;
                size_t offA = ((size_t)b * LSZ + l) * 32 + fr;
                size_t offB = offA + 16;
                float vA = (aA[j] + bA) * scA + shA + xres[offA];
                float vB = (aB[j] + bB) * scB + shB + xres[offB];
                vA = vA >= 0.f ? vA : 0.3f * vA;
                vB = vB >= 0.f ? vB : 0.3f * vB;
                of[offA] = vA;
                of[offB] = vB;
            }
        }
    }
}

extern "C" void kernel_launch(void* const* d_in, const int* in_sizes, int n_in,
                              void* d_out, int out_size, void* d_ws, size_t ws_size,
                              hipStream_t stream) {
    const float* x   = (const float*)d_in[0];
    const float* k1  = (const float*)d_in[1];
    const float* b1  = (const float*)d_in[2];
    const float* g1  = (const float*)d_in[3];
    const float* be1 = (const float*)d_in[4];
    const float* mn1 = (const float*)d_in[5];
    const float* vr1 = (const float*)d_in[6];
    const float* k2  = (const float*)d_in[7];
    const float* b2  = (const float*)d_in[8];
    const float* g2  = (const float*)d_in[9];
    const float* be2 = (const float*)d_in[10];
    const float* mn2 = (const float*)d_in[11];
    const float* vr2 = (const float*)d_in[12];

    f16* ht = (f16*)d_ws;    // [L][32 b][32 c] f16 intermediate (16.8 MB)

    hipLaunchKernelGGL(lc_mfma, dim3(1024), dim3(512), 0, stream,
                       (const void*)x, k1, b1, g1, be1, mn1, vr1,
                       (const float*)nullptr, (void*)ht, 0);
    hipLaunchKernelGGL(lc_mfma, dim3(1024), dim3(512), 0, stream,
                       (const void*)ht, k2, b2, g2, be2, mn2, vr2,
                       x, d_out, 1);
}